// Round 4
// baseline (26661.255 us; speedup 1.0000x reference)
//
#include <hip/hip_runtime.h>
#include <stdint.h>

typedef __attribute__((ext_vector_type(4))) float f32x4;
typedef __attribute__((ext_vector_type(8))) short s16x8;

// ---------------- workspace layout (bytes) ----------------
// XPK : [512] slots x (hi 65536 + lo 65536 shorts)          = 134,217,728
// WL0 : 320 grps x 64 frags x 512 shorts x 2 planes         =  41,943,040
// WL1 : same                                                =  41,943,040
// H0  : 2 slots x 131072 shorts (hi+lo)                     =     524,288
// H1  : same                                                =     524,288
// C0/C1: 64*1024 f32                                        =     262,144 each
#define XPK_OFF  0ull
#define WL0_OFF  134217728ull
#define WL1_OFF  176160768ull
#define H0_OFF   218103808ull
#define H1_OFF   218628096ull
#define C0_OFF   219152384ull
#define C1_OFF   219414528ull
#define WS_NEED  219676672ull

#define OUT_HF 33554432
#define OUT_CF 33685504

static __device__ __forceinline__ float bf2f(unsigned short u){
  unsigned int x = ((unsigned int)u) << 16;
  return __builtin_bit_cast(float, x);
}
static __device__ __forceinline__ unsigned short f2bf(float f){
  unsigned int x = __builtin_bit_cast(unsigned int, f);
  x = x + 0x7FFFu + ((x >> 16) & 1u);   // RNE
  return (unsigned short)(x >> 16);
}
static __device__ __forceinline__ float sigm(float x){ return 1.f/(1.f + __expf(-x)); }
static __device__ __forceinline__ float tanh_(float x){ return 1.f - 2.f/(__expf(2.f*x) + 1.f); }

// ---------------- pack kernels ----------------
// A-side fragment layout (M=batch x K): frag = (k>>5)*4 + (m>>4);
// lane = (m&15) + 16*((k>>3)&3); element = k&7.  hi plane then lo plane (+65536 shorts).
__global__ void k_pack_x(const float* __restrict__ x, unsigned short* __restrict__ xpk){
  int tid = blockIdx.x*256 + threadIdx.x;        // 4,194,304 threads
  int row = tid >> 7, k8 = tid & 127;
  int t = row >> 6, m = row & 63;
  const float* src = x + (long)row*1024 + k8*8;
  int frag = (k8>>2)*4 + (m>>4);
  int ln   = (m&15) + ((k8&3)<<4);
  unsigned short* dst = xpk + (long)t*131072 + frag*512 + ln*8;
  s16x8 hi, lo;
  #pragma unroll
  for (int i=0;i<8;++i){
    float v = src[i];
    unsigned short h = f2bf(v);
    hi[i] = (short)h;
    lo[i] = (short)f2bf(v - bf2f(h));
  }
  *(s16x8*)dst = hi;
  *(s16x8*)(dst + 65536) = lo;
}

// B-side (weights): grp = c*5 + gi (c: 16-col block, gi: 4 gates + tx), fi = k/32.
// frag base = (grp*64+fi)*512; lane = (row&15) + 16*((k>>3)&3); element = k&7.
// Layer 0 A = [h0 | x]  -> gates: k<1024 uses W_all0 h-part (col 1024+k), k>=1024 x-part (col k-1024);
//                          tx: k>=1024 -> wt0[.,k-1024], else 0.
// Layer 1 A = [h0 | h1] -> gates: W_all1[., k] straight; tx: k<1024 -> wt1[., k], else 0.
__global__ void k_pack_w(const float* __restrict__ wall, const float* __restrict__ wt,
                         unsigned short* __restrict__ dst, int layer){
  int tid = blockIdx.x*256 + threadIdx.x;        // 1,310,720 threads
  int grp = tid >> 12;                           // 0..319
  int fi  = (tid >> 6) & 63;                     // k/32
  int slot= tid & 63;
  int jj  = slot & 15;
  int k   = (fi*4 + (slot>>4)) * 8;
  int c   = grp / 5, gi = grp % 5;
  const float* src = nullptr;
  bool zero = false;
  if (gi < 4){
    int row = gi*1024 + c*16 + jj;
    int sk = (layer==0) ? ((k < 1024) ? 1024 + k : k - 1024) : k;
    src = wall + (long)row*2048 + sk;
  } else {
    if (layer == 0){
      if (k >= 1024) src = wt + (long)(c*16+jj)*1024 + (k-1024); else zero = true;
    } else {
      if (k < 1024)  src = wt + (long)(c*16+jj)*1024 + k;        else zero = true;
    }
  }
  s16x8 hi, lo;
  #pragma unroll
  for (int i=0;i<8;++i){
    float v = zero ? 0.f : src[i];
    unsigned short h = f2bf(v);
    hi[i] = (short)h;
    lo[i] = (short)f2bf(v - bf2f(h));
  }
  long base = (long)(grp*64 + fi)*512 + slot*8;
  *(s16x8*)(dst + base) = hi;
  *(s16x8*)(dst + 10485760 + base) = lo;     // lo plane = 20480 frags * 512 shorts
}

// ---------------- per-step kernel ----------------
// Block bid<64: layer 0, c=bid, computes h0[s]   (active s<=511)
// Block bid>=64: layer 1, c=bid-64, computes h1[s-1] (active s>=1)
// 4 waves split K=2048 (waves 0,1 -> A1 k 0..1023; waves 2,3 -> A2 k 1024..2047).
__global__ __launch_bounds__(256, 1) void k_step(
    const unsigned short* __restrict__ xpk,
    const unsigned short* __restrict__ wl0,
    const unsigned short* __restrict__ wl1,
    unsigned short* __restrict__ h0pk,
    unsigned short* __restrict__ h1pk,
    float* __restrict__ c0, float* __restrict__ c1,
    const float* __restrict__ ball0, const float* __restrict__ bt0,
    const float* __restrict__ ball1, const float* __restrict__ bt1,
    float* __restrict__ out, int s)
{
  __shared__ float red[64*84];
  const int bid = blockIdx.x;
  const int layer = bid >> 6;
  const int c = bid & 63;
  if (layer == 0 && s >= 512) return;
  if (layer == 1 && s == 0) return;
  const int tid = threadIdx.x;
  const int lane = tid & 63, w = tid >> 6;

  for (int i = tid; i < 64*84; i += 256) red[i] = 0.f;
  __syncthreads();

  // ---- GEMM phase: 64x80 tile over this wave's K-quarter, bf16x3 ----
  {
    const unsigned short *A1, *A2, *W;
    bool use1, use2;
    if (layer == 0){
      A1 = h0pk + (size_t)((s+1)&1)*131072;   // h0[s-1]
      A2 = xpk  + (size_t)s*131072;           // x[s]
      W  = wl0;  use1 = (s > 0); use2 = true;
    } else {
      A1 = h0pk + (size_t)((s+1)&1)*131072;   // h0[s-1]
      A2 = h1pk + (size_t)(s&1)*131072;       // h1[s-2]
      W  = wl1;  use1 = true; use2 = (s >= 2);
    }
    const s16x8* Abase = (const s16x8*)((w < 2) ? A1 : A2);
    const bool  useA   = (w < 2) ? use1 : use2;
    const s16x8* Bv    = (const s16x8*)W;
    const int a0 = (w & 1) * 64;
    const int b0 = c*320 + w*16;

    f32x4 acc[4][5];
    #pragma unroll
    for (int a=0;a<4;++a)
      #pragma unroll
      for (int b=0;b<5;++b) acc[a][b] = (f32x4){0.f,0.f,0.f,0.f};

    const s16x8 zz = {0,0,0,0,0,0,0,0};
    s16x8 ah[2][4], al[2][4], bh[2][5], bl[2][5];
    auto ldfr = [&](int buf, int ks){
      #pragma unroll
      for (int mf=0; mf<4; ++mf){
        int f = (a0 + ks*4 + mf)*64 + lane;
        ah[buf][mf] = useA ? Abase[f] : zz;
        al[buf][mf] = useA ? Abase[8192 + f] : zz;
      }
      #pragma unroll
      for (int nf=0; nf<5; ++nf){
        int f = (b0 + nf*64 + ks)*64 + lane;
        bh[buf][nf] = Bv[f];
        bl[buf][nf] = Bv[1310720 + f];
      }
    };
    ldfr(0, 0);
    #pragma unroll
    for (int ks=0; ks<16; ++ks){
      const int cur = ks & 1;
      if (ks < 15) ldfr(cur ^ 1, ks + 1);
      #pragma unroll
      for (int mf=0; mf<4; ++mf)
        #pragma unroll
        for (int nf=0; nf<5; ++nf){
          acc[mf][nf] = __builtin_amdgcn_mfma_f32_16x16x32_bf16(ah[cur][mf], bh[cur][nf], acc[mf][nf], 0, 0, 0);
          acc[mf][nf] = __builtin_amdgcn_mfma_f32_16x16x32_bf16(al[cur][mf], bh[cur][nf], acc[mf][nf], 0, 0, 0);
          acc[mf][nf] = __builtin_amdgcn_mfma_f32_16x16x32_bf16(ah[cur][mf], bl[cur][nf], acc[mf][nf], 0, 0, 0);
        }
    }
    // reduce partials into LDS (C/D map: row=(lane>>4)*4+r, col=lane&15)
    #pragma unroll
    for (int mf=0; mf<4; ++mf)
      #pragma unroll
      for (int nf=0; nf<5; ++nf)
        #pragma unroll
        for (int r=0; r<4; ++r){
          int m = mf*16 + (lane>>4)*4 + r;
          int n = nf*16 + (lane&15);
          atomicAdd(&red[m*84 + n], acc[mf][nf][r]);
        }
  }
  __syncthreads();

  // ---- cell phase ----
  const int e = (layer == 0) ? s : s - 1;      // step this block produces
  const float* ball = layer ? ball1 : ball0;
  const float* bt   = layer ? bt1   : bt0;
  float* cs = layer ? c1 : c0;
  unsigned short* hp = (layer ? h1pk : h0pk) + (size_t)(e&1)*131072;

  #pragma unroll
  for (int it=0; it<4; ++it){
    int idx = it*256 + tid;          // 1024 items: 64 m x 16 jj
    int m = idx >> 4, jj = idx & 15;
    int j = c*16 + jj;
    float pre[4];
    #pragma unroll
    for (int g=0; g<4; ++g) pre[g] = red[m*84 + g*16 + jj] + ball[g*1024 + j];
    float tx = red[m*84 + 64 + jj] + bt[j];
    float ii = sigm(pre[0]), ff = sigm(pre[1]), oo = sigm(pre[2]);
    float gt = tanh_(tx * pre[3]);
    float cold = (e == 0) ? 0.f : cs[m*1024 + j];
    float cc = ff*cold + ii*gt;
    cs[m*1024 + j] = cc;
    float hh = oo*tanh_(cc);
    int fr = (j>>5)*4 + (m>>4);
    int ln = (m&15) + (((j>>3)&3)<<4);
    unsigned short hb = f2bf(hh);
    hp[fr*512 + ln*8 + (j&7)] = hb;
    hp[65536 + fr*512 + ln*8 + (j&7)] = f2bf(hh - bf2f(hb));
    if (layer){
      out[(size_t)e*65536 + m*1024 + j] = hh;
      if (e == 511){ out[OUT_HF + 65536 + m*1024 + j] = hh; out[OUT_CF + 65536 + m*1024 + j] = cc; }
    } else if (e == 511){
      out[OUT_HF + m*1024 + j] = hh; out[OUT_CF + m*1024 + j] = cc;
    }
  }
}

extern "C" void kernel_launch(void* const* d_in, const int* in_sizes, int n_in,
                              void* d_out, int out_size, void* d_ws, size_t ws_size,
                              hipStream_t stream)
{
  (void)in_sizes; (void)n_in;
  const float* x     = (const float*)d_in[0];
  const float* wall0 = (const float*)d_in[1];
  const float* ball0 = (const float*)d_in[2];
  const float* wt0   = (const float*)d_in[3];
  const float* bt0   = (const float*)d_in[4];
  const float* wall1 = (const float*)d_in[5];
  const float* ball1 = (const float*)d_in[6];
  const float* wt1   = (const float*)d_in[7];
  const float* bt1   = (const float*)d_in[8];
  float* out = (float*)d_out;
  char* ws = (char*)d_ws;

  if (ws_size < WS_NEED){
    hipMemsetAsync(d_out, 0, (size_t)out_size*4, stream);  // visible failure, no OOB
    return;
  }

  unsigned short* xpk = (unsigned short*)(ws + XPK_OFF);
  unsigned short* wl0 = (unsigned short*)(ws + WL0_OFF);
  unsigned short* wl1 = (unsigned short*)(ws + WL1_OFF);
  unsigned short* h0p = (unsigned short*)(ws + H0_OFF);
  unsigned short* h1p = (unsigned short*)(ws + H1_OFF);
  float* c0 = (float*)(ws + C0_OFF);
  float* c1 = (float*)(ws + C1_OFF);

  k_pack_x<<<16384, 256, 0, stream>>>(x, xpk);
  k_pack_w<<<5120, 256, 0, stream>>>(wall0, wt0, wl0, 0);
  k_pack_w<<<5120, 256, 0, stream>>>(wall1, wt1, wl1, 1);

  for (int s = 0; s <= 512; ++s){
    k_step<<<128, 256, 0, stream>>>(xpk, wl0, wl1, h0p, h1p, c0, c1,
                                    ball0, bt0, ball1, bt1, out, s);
  }
}

// Round 5
// 8765.508 us; speedup vs baseline: 3.0416x; 3.0416x over previous
//
#include <hip/hip_runtime.h>
#include <stdint.h>

typedef __attribute__((ext_vector_type(4))) float f32x4;
typedef __attribute__((ext_vector_type(8))) short s16x8;

// ---------------- workspace layout (bytes) ----------------
#define XPK_OFF  0ull
#define WL0_OFF  134217728ull
#define WL1_OFF  176160768ull
#define H0_OFF   218103808ull
#define H1_OFF   218628096ull
#define C0_OFF   219152384ull
#define C1_OFF   219414528ull
#define WS_NEED  219676672ull

#define OUT_HF 33554432
#define OUT_CF 33685504

static __device__ __forceinline__ float bf2f(unsigned short u){
  unsigned int x = ((unsigned int)u) << 16;
  return __builtin_bit_cast(float, x);
}
static __device__ __forceinline__ unsigned short f2bf(float f){
  unsigned int x = __builtin_bit_cast(unsigned int, f);
  x = x + 0x7FFFu + ((x >> 16) & 1u);   // RNE
  return (unsigned short)(x >> 16);
}
static __device__ __forceinline__ float sigm(float x){ return 1.f/(1.f + __expf(-x)); }
static __device__ __forceinline__ float tanh_(float x){ return 1.f - 2.f/(__expf(2.f*x) + 1.f); }

// ---------------- pack kernels (unchanged from validated round 4) ----------------
__global__ void k_pack_x(const float* __restrict__ x, unsigned short* __restrict__ xpk){
  int tid = blockIdx.x*256 + threadIdx.x;        // 4,194,304 threads
  int row = tid >> 7, k8 = tid & 127;
  int t = row >> 6, m = row & 63;
  const float* src = x + (long)row*1024 + k8*8;
  int frag = (k8>>2)*4 + (m>>4);
  int ln   = (m&15) + ((k8&3)<<4);
  unsigned short* dst = xpk + (long)t*131072 + frag*512 + ln*8;
  s16x8 hi, lo;
  #pragma unroll
  for (int i=0;i<8;++i){
    float v = src[i];
    unsigned short h = f2bf(v);
    hi[i] = (short)h;
    lo[i] = (short)f2bf(v - bf2f(h));
  }
  *(s16x8*)dst = hi;
  *(s16x8*)(dst + 65536) = lo;
}

__global__ void k_pack_w(const float* __restrict__ wall, const float* __restrict__ wt,
                         unsigned short* __restrict__ dst, int layer){
  int tid = blockIdx.x*256 + threadIdx.x;        // 1,310,720 threads
  int grp = tid >> 12;                           // 0..319
  int fi  = (tid >> 6) & 63;                     // k/32
  int slot= tid & 63;
  int jj  = slot & 15;
  int k   = (fi*4 + (slot>>4)) * 8;
  int c   = grp / 5, gi = grp % 5;
  const float* src = nullptr;
  bool zero = false;
  if (gi < 4){
    int row = gi*1024 + c*16 + jj;
    int sk = (layer==0) ? ((k < 1024) ? 1024 + k : k - 1024) : k;
    src = wall + (long)row*2048 + sk;
  } else {
    if (layer == 0){
      if (k >= 1024) src = wt + (long)(c*16+jj)*1024 + (k-1024); else zero = true;
    } else {
      if (k < 1024)  src = wt + (long)(c*16+jj)*1024 + k;        else zero = true;
    }
  }
  s16x8 hi, lo;
  #pragma unroll
  for (int i=0;i<8;++i){
    float v = zero ? 0.f : src[i];
    unsigned short h = f2bf(v);
    hi[i] = (short)h;
    lo[i] = (short)f2bf(v - bf2f(h));
  }
  long base = (long)(grp*64 + fi)*512 + slot*8;
  *(s16x8*)(dst + base) = hi;
  *(s16x8*)(dst + 10485760 + base) = lo;
}

// ---------------- per-step kernel ----------------
// 256 blocks. bid -> xcd = bid&7, t = bid>>3, mh = t&1, slot = t>>1,
// pid = slot*8+xcd: layer = pid>>6, c = pid&63. The two mh blocks of a pair
// share the same bid%8 (same XCD heuristic) so B weight re-reads hit that L2.
// 4 waves K-split (waves 0,1 -> A1 k 0..1023; waves 2,3 -> A2 k 1024..2047),
// each wave covers m-rows mh*32..mh*32+31 (A m-frags mh*2, mh*2+1).
__global__ __launch_bounds__(256, 1) void k_step(
    const unsigned short* __restrict__ xpk,
    const unsigned short* __restrict__ wl0,
    const unsigned short* __restrict__ wl1,
    unsigned short* __restrict__ h0pk,
    unsigned short* __restrict__ h1pk,
    float* __restrict__ c0, float* __restrict__ c1,
    const float* __restrict__ ball0, const float* __restrict__ bt0,
    const float* __restrict__ ball1, const float* __restrict__ bt1,
    float* __restrict__ out, int s)
{
  __shared__ float R0[32*84];
  __shared__ float R1[32*84];
  const int bid = blockIdx.x;
  const int xcd = bid & 7, tq = bid >> 3;
  const int mh = tq & 1, slotq = tq >> 1;
  const int pid = (slotq << 3) | xcd;
  const int layer = pid >> 6;
  const int c = pid & 63;
  if (layer == 0 && s >= 512) return;
  if (layer == 1 && s == 0) return;
  const int tid = threadIdx.x;
  const int lane = tid & 63, w = tid >> 6;

  // ---- GEMM phase: 32x80 tile over this wave's K-quarter, bf16x3 ----
  f32x4 acc[2][5];
  #pragma unroll
  for (int a=0;a<2;++a)
    #pragma unroll
    for (int b=0;b<5;++b) acc[a][b] = (f32x4){0.f,0.f,0.f,0.f};
  {
    const unsigned short *A1, *A2, *W;
    bool use1, use2;
    if (layer == 0){
      A1 = h0pk + (size_t)((s+1)&1)*131072;   // h0[s-1]
      A2 = xpk  + (size_t)s*131072;           // x[s]
      W  = wl0;  use1 = (s > 0); use2 = true;
    } else {
      A1 = h0pk + (size_t)((s+1)&1)*131072;   // h0[s-1]
      A2 = h1pk + (size_t)(s&1)*131072;       // h1[s-2]
      W  = wl1;  use1 = true; use2 = (s >= 2);
    }
    const s16x8* Abase = (const s16x8*)((w < 2) ? A1 : A2);
    const bool  useA   = (w < 2) ? use1 : use2;
    const s16x8* Bv    = (const s16x8*)W;
    const int a0 = (w & 1)*64 + mh*2;
    const int b0 = c*320 + w*16;
    // tx weight block is structurally zero in: L0 h-half (waves 0,1); L1 h1-half (waves 2,3)
    const bool doTx = (layer == 0) ? (w >= 2) : (w < 2);

    const s16x8 zz = {0,0,0,0,0,0,0,0};
    s16x8 ah[2][2], al[2][2], bh[2][5], bl[2][5];
    auto ldfr = [&](int buf, int ks){
      #pragma unroll
      for (int mf=0; mf<2; ++mf){
        int f = (a0 + ks*4 + mf)*64 + lane;
        ah[buf][mf] = useA ? Abase[f] : zz;
        al[buf][mf] = useA ? Abase[8192 + f] : zz;
      }
      #pragma unroll
      for (int nf=0; nf<4; ++nf){
        int f = (b0 + nf*64 + ks)*64 + lane;
        bh[buf][nf] = Bv[f];
        bl[buf][nf] = Bv[1310720 + f];
      }
      if (doTx){
        int f = (b0 + 4*64 + ks)*64 + lane;
        bh[buf][4] = Bv[f];
        bl[buf][4] = Bv[1310720 + f];
      }
    };
    ldfr(0, 0);
    #pragma unroll
    for (int ks=0; ks<16; ++ks){
      const int cur = ks & 1;
      if (ks < 15) ldfr(cur ^ 1, ks + 1);
      #pragma unroll
      for (int mf=0; mf<2; ++mf)
        #pragma unroll
        for (int nf=0; nf<4; ++nf){
          acc[mf][nf] = __builtin_amdgcn_mfma_f32_16x16x32_bf16(ah[cur][mf], bh[cur][nf], acc[mf][nf], 0, 0, 0);
          acc[mf][nf] = __builtin_amdgcn_mfma_f32_16x16x32_bf16(al[cur][mf], bh[cur][nf], acc[mf][nf], 0, 0, 0);
          acc[mf][nf] = __builtin_amdgcn_mfma_f32_16x16x32_bf16(ah[cur][mf], bl[cur][nf], acc[mf][nf], 0, 0, 0);
        }
      if (doTx){
        #pragma unroll
        for (int mf=0; mf<2; ++mf){
          acc[mf][4] = __builtin_amdgcn_mfma_f32_16x16x32_bf16(ah[cur][mf], bh[cur][4], acc[mf][4], 0, 0, 0);
          acc[mf][4] = __builtin_amdgcn_mfma_f32_16x16x32_bf16(al[cur][mf], bh[cur][4], acc[mf][4], 0, 0, 0);
          acc[mf][4] = __builtin_amdgcn_mfma_f32_16x16x32_bf16(ah[cur][mf], bl[cur][4], acc[mf][4], 0, 0, 0);
        }
      }
    }
  }

  // ---- reduce: two-buffer non-atomic (w0/w1 write, w2/w3 add) ----
  {
    float* R = (w & 1) ? R1 : R0;
    if (w < 2){
      #pragma unroll
      for (int mf=0; mf<2; ++mf)
        #pragma unroll
        for (int nf=0; nf<5; ++nf)
          #pragma unroll
          for (int r=0; r<4; ++r){
            int m = mf*16 + (lane>>4)*4 + r;
            int n = nf*16 + (lane&15);
            R[m*84 + n] = acc[mf][nf][r];
          }
    }
    __syncthreads();
    if (w >= 2){
      #pragma unroll
      for (int mf=0; mf<2; ++mf)
        #pragma unroll
        for (int nf=0; nf<5; ++nf)
          #pragma unroll
          for (int r=0; r<4; ++r){
            int m = mf*16 + (lane>>4)*4 + r;
            int n = nf*16 + (lane&15);
            R[m*84 + n] += acc[mf][nf][r];
          }
    }
    __syncthreads();
  }

  // ---- cell phase (32 rows x 16 cols = 512 items over 256 threads) ----
  const int e = (layer == 0) ? s : s - 1;
  const float* ball = layer ? ball1 : ball0;
  const float* bt   = layer ? bt1   : bt0;
  float* cs = layer ? c1 : c0;
  unsigned short* hp = (layer ? h1pk : h0pk) + (size_t)(e&1)*131072;

  #pragma unroll
  for (int it=0; it<2; ++it){
    int idx = it*256 + tid;
    int ml = idx >> 4, jj = idx & 15;
    int m = mh*32 + ml;
    int j = c*16 + jj;
    float pre[4];
    #pragma unroll
    for (int g=0; g<4; ++g)
      pre[g] = R0[ml*84 + g*16 + jj] + R1[ml*84 + g*16 + jj] + ball[g*1024 + j];
    float tx = R0[ml*84 + 64 + jj] + R1[ml*84 + 64 + jj] + bt[j];
    float ii = sigm(pre[0]), ff = sigm(pre[1]), oo = sigm(pre[2]);
    float gt = tanh_(tx * pre[3]);
    float cold = (e == 0) ? 0.f : cs[m*1024 + j];
    float cc = ff*cold + ii*gt;
    cs[m*1024 + j] = cc;
    float hh = oo*tanh_(cc);
    int fr = (j>>5)*4 + (m>>4);
    int ln = (m&15) + (((j>>3)&3)<<4);
    unsigned short hb = f2bf(hh);
    hp[fr*512 + ln*8 + (j&7)] = hb;
    hp[65536 + fr*512 + ln*8 + (j&7)] = f2bf(hh - bf2f(hb));
    if (layer){
      out[(size_t)e*65536 + m*1024 + j] = hh;
      if (e == 511){ out[OUT_HF + 65536 + m*1024 + j] = hh; out[OUT_CF + 65536 + m*1024 + j] = cc; }
    } else if (e == 511){
      out[OUT_HF + m*1024 + j] = hh; out[OUT_CF + m*1024 + j] = cc;
    }
  }
}

extern "C" void kernel_launch(void* const* d_in, const int* in_sizes, int n_in,
                              void* d_out, int out_size, void* d_ws, size_t ws_size,
                              hipStream_t stream)
{
  (void)in_sizes; (void)n_in;
  const float* x     = (const float*)d_in[0];
  const float* wall0 = (const float*)d_in[1];
  const float* ball0 = (const float*)d_in[2];
  const float* wt0   = (const float*)d_in[3];
  const float* bt0   = (const float*)d_in[4];
  const float* wall1 = (const float*)d_in[5];
  const float* ball1 = (const float*)d_in[6];
  const float* wt1   = (const float*)d_in[7];
  const float* bt1   = (const float*)d_in[8];
  float* out = (float*)d_out;
  char* ws = (char*)d_ws;

  if (ws_size < WS_NEED){
    hipMemsetAsync(d_out, 0, (size_t)out_size*4, stream);  // visible failure, no OOB
    return;
  }

  unsigned short* xpk = (unsigned short*)(ws + XPK_OFF);
  unsigned short* wl0 = (unsigned short*)(ws + WL0_OFF);
  unsigned short* wl1 = (unsigned short*)(ws + WL1_OFF);
  unsigned short* h0p = (unsigned short*)(ws + H0_OFF);
  unsigned short* h1p = (unsigned short*)(ws + H1_OFF);
  float* c0 = (float*)(ws + C0_OFF);
  float* c1 = (float*)(ws + C1_OFF);

  k_pack_x<<<16384, 256, 0, stream>>>(x, xpk);
  k_pack_w<<<5120, 256, 0, stream>>>(wall0, wt0, wl0, 0);
  k_pack_w<<<5120, 256, 0, stream>>>(wall1, wt1, wl1, 1);

  for (int s = 0; s <= 512; ++s){
    k_step<<<256, 256, 0, stream>>>(xpk, wl0, wl1, h0p, h1p, c0, c1,
                                    ball0, bt0, ball1, bt1, out, s);
  }
}

// Round 6
// 8320.172 us; speedup vs baseline: 3.2044x; 1.0535x over previous
//
#include <hip/hip_runtime.h>
#include <stdint.h>

typedef __attribute__((ext_vector_type(4))) float f32x4;
typedef __attribute__((ext_vector_type(8))) short s16x8;

// ---------------- workspace layout (bytes) ----------------
#define XPK_OFF  0ull
#define WL0_OFF  134217728ull
#define WL1_OFF  176160768ull
#define H0_OFF   218103808ull
#define H1_OFF   218628096ull
#define C0_OFF   219152384ull
#define C1_OFF   219414528ull
#define WS_NEED  219676672ull

#define OUT_HF 33554432
#define OUT_CF 33685504

static __device__ __forceinline__ float bf2f(unsigned short u){
  unsigned int x = ((unsigned int)u) << 16;
  return __builtin_bit_cast(float, x);
}
static __device__ __forceinline__ unsigned short f2bf(float f){
  unsigned int x = __builtin_bit_cast(unsigned int, f);
  x = x + 0x7FFFu + ((x >> 16) & 1u);   // RNE
  return (unsigned short)(x >> 16);
}
static __device__ __forceinline__ float sigm(float x){ return 1.f/(1.f + __expf(-x)); }
static __device__ __forceinline__ float tanh_(float x){ return 1.f - 2.f/(__expf(2.f*x) + 1.f); }

// ---------------- pack kernels (unchanged from validated round 4) ----------------
__global__ void k_pack_x(const float* __restrict__ x, unsigned short* __restrict__ xpk){
  int tid = blockIdx.x*256 + threadIdx.x;        // 4,194,304 threads
  int row = tid >> 7, k8 = tid & 127;
  int t = row >> 6, m = row & 63;
  const float* src = x + (long)row*1024 + k8*8;
  int frag = (k8>>2)*4 + (m>>4);
  int ln   = (m&15) + ((k8&3)<<4);
  unsigned short* dst = xpk + (long)t*131072 + frag*512 + ln*8;
  s16x8 hi, lo;
  #pragma unroll
  for (int i=0;i<8;++i){
    float v = src[i];
    unsigned short h = f2bf(v);
    hi[i] = (short)h;
    lo[i] = (short)f2bf(v - bf2f(h));
  }
  *(s16x8*)dst = hi;
  *(s16x8*)(dst + 65536) = lo;
}

__global__ void k_pack_w(const float* __restrict__ wall, const float* __restrict__ wt,
                         unsigned short* __restrict__ dst, int layer){
  int tid = blockIdx.x*256 + threadIdx.x;        // 1,310,720 threads
  int grp = tid >> 12;                           // 0..319
  int fi  = (tid >> 6) & 63;                     // k/32
  int slot= tid & 63;
  int jj  = slot & 15;
  int k   = (fi*4 + (slot>>4)) * 8;
  int c   = grp / 5, gi = grp % 5;
  const float* src = nullptr;
  bool zero = false;
  if (gi < 4){
    int row = gi*1024 + c*16 + jj;
    int sk = (layer==0) ? ((k < 1024) ? 1024 + k : k - 1024) : k;
    src = wall + (long)row*2048 + sk;
  } else {
    if (layer == 0){
      if (k >= 1024) src = wt + (long)(c*16+jj)*1024 + (k-1024); else zero = true;
    } else {
      if (k < 1024)  src = wt + (long)(c*16+jj)*1024 + k;        else zero = true;
    }
  }
  s16x8 hi, lo;
  #pragma unroll
  for (int i=0;i<8;++i){
    float v = zero ? 0.f : src[i];
    unsigned short h = f2bf(v);
    hi[i] = (short)h;
    lo[i] = (short)f2bf(v - bf2f(h));
  }
  long base = (long)(grp*64 + fi)*512 + slot*8;
  *(s16x8*)(dst + base) = hi;
  *(s16x8*)(dst + 10485760 + base) = lo;
}

// ---------------- per-step kernel ----------------
// 256 blocks. bid -> xcd = bid&7, t = bid>>3, mh = t&1, slot = t>>1,
// pid = slot*8+xcd: layer = pid>>6, c = pid&63. The two mh blocks of a pair
// share the same bid%8 (same XCD heuristic) so B weight re-reads hit that L2.
// 4 waves K-split (waves 0,1 -> A1 k 0..1023; waves 2,3 -> A2 k 1024..2047),
// each wave covers m-rows mh*32..mh*32+31 (A m-frags mh*2, mh*2+1).
__global__ __launch_bounds__(256, 1) void k_step(
    const unsigned short* __restrict__ xpk,
    const unsigned short* __restrict__ wl0,
    const unsigned short* __restrict__ wl1,
    unsigned short* __restrict__ h0pk,
    unsigned short* __restrict__ h1pk,
    float* __restrict__ c0, float* __restrict__ c1,
    const float* __restrict__ ball0, const float* __restrict__ bt0,
    const float* __restrict__ ball1, const float* __restrict__ bt1,
    float* __restrict__ out, int s)
{
  __shared__ float R0[32*84];
  __shared__ float R1[32*84];
  const int bid = blockIdx.x;
  const int xcd = bid & 7, tq = bid >> 3;
  const int mh = tq & 1, slotq = tq >> 1;
  const int pid = (slotq << 3) | xcd;
  const int layer = pid >> 6;
  const int c = pid & 63;
  if (layer == 0 && s >= 512) return;
  if (layer == 1 && s == 0) return;
  const int tid = threadIdx.x;
  const int lane = tid & 63, w = tid >> 6;

  // ---- GEMM phase: 32x80 tile over this wave's K-quarter, bf16x3 ----
  // 3-stage software pipeline (prefetch distance 2) to cover L2/L3 latency at
  // 1 wave/SIMD occupancy.
  f32x4 acc[2][5];
  #pragma unroll
  for (int a=0;a<2;++a)
    #pragma unroll
    for (int b=0;b<5;++b) acc[a][b] = (f32x4){0.f,0.f,0.f,0.f};
  {
    const unsigned short *A1, *A2, *W;
    bool use1, use2;
    if (layer == 0){
      A1 = h0pk + (size_t)((s+1)&1)*131072;   // h0[s-1]
      A2 = xpk  + (size_t)s*131072;           // x[s]
      W  = wl0;  use1 = (s > 0); use2 = true;
    } else {
      A1 = h0pk + (size_t)((s+1)&1)*131072;   // h0[s-1]
      A2 = h1pk + (size_t)(s&1)*131072;       // h1[s-2]
      W  = wl1;  use1 = true; use2 = (s >= 2);
    }
    const s16x8* Abase = (const s16x8*)((w < 2) ? A1 : A2);
    const bool  useA   = (w < 2) ? use1 : use2;
    const s16x8* Bv    = (const s16x8*)W;
    const int a0 = (w & 1)*64 + mh*2;
    const int b0 = c*320 + w*16;
    // tx weight block is structurally zero in: L0 h-half (waves 0,1); L1 h1-half (waves 2,3)
    const bool doTx = (layer == 0) ? (w >= 2) : (w < 2);

    const s16x8 zz = {0,0,0,0,0,0,0,0};
    s16x8 ah[3][2], al[3][2], bh[3][5], bl[3][5];
    auto ldfr = [&](int buf, int ks){
      #pragma unroll
      for (int mf=0; mf<2; ++mf){
        int f = (a0 + ks*4 + mf)*64 + lane;
        ah[buf][mf] = useA ? Abase[f] : zz;
        al[buf][mf] = useA ? Abase[8192 + f] : zz;
      }
      #pragma unroll
      for (int nf=0; nf<4; ++nf){
        int f = (b0 + nf*64 + ks)*64 + lane;
        bh[buf][nf] = Bv[f];
        bl[buf][nf] = Bv[1310720 + f];
      }
      if (doTx){
        int f = (b0 + 4*64 + ks)*64 + lane;
        bh[buf][4] = Bv[f];
        bl[buf][4] = Bv[1310720 + f];
      }
    };
    ldfr(0, 0);
    ldfr(1, 1);
    #pragma unroll
    for (int ks=0; ks<16; ++ks){
      const int cur = ks % 3;
      if (ks < 14) ldfr((ks + 2) % 3, ks + 2);
      #pragma unroll
      for (int mf=0; mf<2; ++mf)
        #pragma unroll
        for (int nf=0; nf<4; ++nf){
          acc[mf][nf] = __builtin_amdgcn_mfma_f32_16x16x32_bf16(ah[cur][mf], bh[cur][nf], acc[mf][nf], 0, 0, 0);
          acc[mf][nf] = __builtin_amdgcn_mfma_f32_16x16x32_bf16(al[cur][mf], bh[cur][nf], acc[mf][nf], 0, 0, 0);
          acc[mf][nf] = __builtin_amdgcn_mfma_f32_16x16x32_bf16(ah[cur][mf], bl[cur][nf], acc[mf][nf], 0, 0, 0);
        }
      if (doTx){
        #pragma unroll
        for (int mf=0; mf<2; ++mf){
          acc[mf][4] = __builtin_amdgcn_mfma_f32_16x16x32_bf16(ah[cur][mf], bh[cur][4], acc[mf][4], 0, 0, 0);
          acc[mf][4] = __builtin_amdgcn_mfma_f32_16x16x32_bf16(al[cur][mf], bh[cur][4], acc[mf][4], 0, 0, 0);
          acc[mf][4] = __builtin_amdgcn_mfma_f32_16x16x32_bf16(ah[cur][mf], bl[cur][4], acc[mf][4], 0, 0, 0);
        }
      }
    }
  }

  // ---- reduce: two-buffer non-atomic (w0/w1 write, w2/w3 add) ----
  {
    float* R = (w & 1) ? R1 : R0;
    if (w < 2){
      #pragma unroll
      for (int mf=0; mf<2; ++mf)
        #pragma unroll
        for (int nf=0; nf<5; ++nf)
          #pragma unroll
          for (int r=0; r<4; ++r){
            int m = mf*16 + (lane>>4)*4 + r;
            int n = nf*16 + (lane&15);
            R[m*84 + n] = acc[mf][nf][r];
          }
    }
    __syncthreads();
    if (w >= 2){
      #pragma unroll
      for (int mf=0; mf<2; ++mf)
        #pragma unroll
        for (int nf=0; nf<5; ++nf)
          #pragma unroll
          for (int r=0; r<4; ++r){
            int m = mf*16 + (lane>>4)*4 + r;
            int n = nf*16 + (lane&15);
            R[m*84 + n] += acc[mf][nf][r];
          }
    }
    __syncthreads();
  }

  // ---- cell phase (32 rows x 16 cols = 512 items over 256 threads) ----
  const int e = (layer == 0) ? s : s - 1;
  const float* ball = layer ? ball1 : ball0;
  const float* bt   = layer ? bt1   : bt0;
  float* cs = layer ? c1 : c0;
  unsigned short* hp = (layer ? h1pk : h0pk) + (size_t)(e&1)*131072;

  #pragma unroll
  for (int it=0; it<2; ++it){
    int idx = it*256 + tid;
    int ml = idx >> 4, jj = idx & 15;
    int m = mh*32 + ml;
    int j = c*16 + jj;
    float pre[4];
    #pragma unroll
    for (int g=0; g<4; ++g)
      pre[g] = R0[ml*84 + g*16 + jj] + R1[ml*84 + g*16 + jj] + ball[g*1024 + j];
    float tx = R0[ml*84 + 64 + jj] + R1[ml*84 + 64 + jj] + bt[j];
    float ii = sigm(pre[0]), ff = sigm(pre[1]), oo = sigm(pre[2]);
    float gt = tanh_(tx * pre[3]);
    float cold = (e == 0) ? 0.f : cs[m*1024 + j];
    float cc = ff*cold + ii*gt;
    cs[m*1024 + j] = cc;
    float hh = oo*tanh_(cc);
    int fr = (j>>5)*4 + (m>>4);
    int ln = (m&15) + (((j>>3)&3)<<4);
    unsigned short hb = f2bf(hh);
    hp[fr*512 + ln*8 + (j&7)] = hb;
    hp[65536 + fr*512 + ln*8 + (j&7)] = f2bf(hh - bf2f(hb));
    if (layer){
      out[(size_t)e*65536 + m*1024 + j] = hh;
      if (e == 511){ out[OUT_HF + 65536 + m*1024 + j] = hh; out[OUT_CF + 65536 + m*1024 + j] = cc; }
    } else if (e == 511){
      out[OUT_HF + m*1024 + j] = hh; out[OUT_CF + m*1024 + j] = cc;
    }
  }
}

extern "C" void kernel_launch(void* const* d_in, const int* in_sizes, int n_in,
                              void* d_out, int out_size, void* d_ws, size_t ws_size,
                              hipStream_t stream)
{
  (void)in_sizes; (void)n_in;
  const float* x     = (const float*)d_in[0];
  const float* wall0 = (const float*)d_in[1];
  const float* ball0 = (const float*)d_in[2];
  const float* wt0   = (const float*)d_in[3];
  const float* bt0   = (const float*)d_in[4];
  const float* wall1 = (const float*)d_in[5];
  const float* ball1 = (const float*)d_in[6];
  const float* wt1   = (const float*)d_in[7];
  const float* bt1   = (const float*)d_in[8];
  float* out = (float*)d_out;
  char* ws = (char*)d_ws;

  if (ws_size < WS_NEED){
    hipMemsetAsync(d_out, 0, (size_t)out_size*4, stream);  // visible failure, no OOB
    return;
  }

  unsigned short* xpk = (unsigned short*)(ws + XPK_OFF);
  unsigned short* wl0 = (unsigned short*)(ws + WL0_OFF);
  unsigned short* wl1 = (unsigned short*)(ws + WL1_OFF);
  unsigned short* h0p = (unsigned short*)(ws + H0_OFF);
  unsigned short* h1p = (unsigned short*)(ws + H1_OFF);
  float* c0 = (float*)(ws + C0_OFF);
  float* c1 = (float*)(ws + C1_OFF);

  k_pack_x<<<16384, 256, 0, stream>>>(x, xpk);
  k_pack_w<<<5120, 256, 0, stream>>>(wall0, wt0, wl0, 0);
  k_pack_w<<<5120, 256, 0, stream>>>(wall1, wt1, wl1, 1);

  for (int s = 0; s <= 512; ++s){
    k_step<<<256, 256, 0, stream>>>(xpk, wl0, wl1, h0p, h1p, c0, c1,
                                    ball0, bt0, ball1, bt1, out, s);
  }
}